// Round 2
// baseline (747.699 us; speedup 1.0000x reference)
//
#include <hip/hip_runtime.h>
#include <stdint.h>

#define Bn 16
#define Sn 256
#define Vn 21128
#define NV4 5282      // Vn/4 exactly
#define RANKn 32
#define BEAMn 64
#define HBINS 4096
#define CAPn 512

__device__ __forceinline__ unsigned f2o(unsigned b) {  // float bits -> order-preserving uint
    return (b & 0x80000000u) ? ~b : (b | 0x80000000u);
}
__device__ __forceinline__ float o2f(unsigned u) {
    unsigned b = (u & 0x80000000u) ? (u ^ 0x80000000u) : ~u;
    return __uint_as_float(b);
}

// One block per (b,s) row: radix-select top-64, force-include target.
__global__ __launch_bounds__(256) void topk_kernel(const float* __restrict__ emis,
                                                   const int* __restrict__ targets,
                                                   int* __restrict__ beam_idx,
                                                   float* __restrict__ beam_val) {
    const int row = blockIdx.x;            // b*Sn + s
    const float* __restrict__ rowp = emis + (size_t)row * Vn;
    const int tgt = targets[row];
    __shared__ unsigned hist[HBINS];
    __shared__ unsigned csum[256];
    __shared__ unsigned cu[CAPn];
    __shared__ int      cix[CAPn];
    __shared__ int      selidx[BEAMn];
    __shared__ float    selval[BEAMn];
    __shared__ unsigned ccount;
    __shared__ int      binstar;
    __shared__ int      chunkc;
    __shared__ int      hastgt;
    const int t = threadIdx.x;
    for (int i = t; i < HBINS; i += 256) hist[i] = 0;
    if (t == 0) { ccount = 0; hastgt = 0; }
    __syncthreads();
    uint4 vals[21];
    #pragma unroll
    for (int it = 0; it < 21; ++it) {
        int v4 = t + it * 256;
        if (v4 < NV4) {
            const uint4 raw = ((const uint4*)rowp)[v4];
            uint4 u;
            u.x = f2o(raw.x); u.y = f2o(raw.y); u.z = f2o(raw.z); u.w = f2o(raw.w);
            vals[it] = u;
            atomicAdd(&hist[u.x >> 20], 1u);
            atomicAdd(&hist[u.y >> 20], 1u);
            atomicAdd(&hist[u.z >> 20], 1u);
            atomicAdd(&hist[u.w >> 20], 1u);
        }
    }
    __syncthreads();
    // coarse sums: 16 bins per thread
    unsigned cs = 0;
    #pragma unroll
    for (int i = 0; i < 16; ++i) cs += hist[t * 16 + i];
    csum[t] = cs;
    __syncthreads();
    // inclusive SUFFIX scan (Hillis-Steele)
    for (int off = 1; off < 256; off <<= 1) {
        unsigned v = csum[t] + ((t + off < 256) ? csum[t + off] : 0u);
        __syncthreads();
        csum[t] = v;
        __syncthreads();
    }
    if (csum[t] >= BEAMn && (t == 255 || csum[t + 1] < BEAMn)) chunkc = t;
    __syncthreads();
    if (t == 0) {
        int tc = chunkc;
        unsigned acc = (tc == 255) ? 0u : csum[tc + 1];
        int bs = tc * 16;
        for (int b2 = tc * 16 + 15; b2 >= tc * 16; --b2) {
            acc += hist[b2];
            if (acc >= BEAMn) { bs = b2; break; }
        }
        binstar = bs;
    }
    __syncthreads();
    const unsigned bstar = (unsigned)binstar;
    // collect candidates (bin >= bstar) from register-cached values
    #pragma unroll
    for (int it = 0; it < 21; ++it) {
        int v4 = t + it * 256;
        if (v4 < NV4) {
            uint4 u = vals[it];
            int bi = v4 * 4;
            if ((u.x >> 20) >= bstar) { unsigned p = atomicAdd(&ccount, 1u); if (p < CAPn) { cu[p] = u.x; cix[p] = bi;     } }
            if ((u.y >> 20) >= bstar) { unsigned p = atomicAdd(&ccount, 1u); if (p < CAPn) { cu[p] = u.y; cix[p] = bi + 1; } }
            if ((u.z >> 20) >= bstar) { unsigned p = atomicAdd(&ccount, 1u); if (p < CAPn) { cu[p] = u.z; cix[p] = bi + 2; } }
            if ((u.w >> 20) >= bstar) { unsigned p = atomicAdd(&ccount, 1u); if (p < CAPn) { cu[p] = u.w; cix[p] = bi + 3; } }
        }
    }
    __syncthreads();
    const int C = (int)min(ccount, (unsigned)CAPn);
    // exact rank (value desc, index asc tie-break — matches JAX stable top_k)
    for (int p = t; p < C; p += 256) {
        unsigned up = cu[p]; int ip = cix[p];
        int rank = 0;
        for (int q = 0; q < C; ++q) {
            unsigned uq = cu[q];
            rank += (uq > up) || (uq == up && cix[q] < ip);
        }
        if (rank < BEAMn) { selidx[rank] = ip; selval[rank] = o2f(up); }
    }
    __syncthreads();
    if (t < BEAMn && selidx[t] == tgt) hastgt = 1;
    __syncthreads();
    if (t == 0 && !hastgt) { selidx[BEAMn - 1] = tgt; selval[BEAMn - 1] = rowp[tgt]; }
    __syncthreads();
    if (t < BEAMn) {
        beam_idx[(size_t)row * BEAMn + t] = selidx[t];
        beam_val[(size_t)row * BEAMn + t] = selval[t];
    }
}

// beam_trans[b,k,i,j] = dot32(E1[beam[b,k,i]], E2[beam[b,k+1,j]])
#define TPAD 68
__global__ __launch_bounds__(256) void trans_kernel(const float* __restrict__ E1,
                                                    const float* __restrict__ E2,
                                                    const int* __restrict__ beam_idx,
                                                    float* __restrict__ trans) {
    const int blk = blockIdx.x;           // b*(Sn-1) + k
    const int b = blk / (Sn - 1);
    const int k = blk - b * (Sn - 1);
    const int* bi = beam_idx + ((size_t)(b * Sn + k)) * BEAMn;
    const int* bj = beam_idx + ((size_t)(b * Sn + k + 1)) * BEAMn;
    __shared__ float e1t[RANKn][TPAD];   // [r][i], 272B row stride (16B aligned)
    __shared__ float e2t[RANKn][TPAD];
    const int t = threadIdx.x;
    {
        const int row = t >> 2, q = t & 3;
        const int rb = q * 8;
        int i1 = bi[row];
        const float4* s1 = (const float4*)(E1 + (size_t)i1 * RANKn) + q * 2;
        float4 a0 = s1[0], a1 = s1[1];
        e1t[rb + 0][row] = a0.x; e1t[rb + 1][row] = a0.y; e1t[rb + 2][row] = a0.z; e1t[rb + 3][row] = a0.w;
        e1t[rb + 4][row] = a1.x; e1t[rb + 5][row] = a1.y; e1t[rb + 6][row] = a1.z; e1t[rb + 7][row] = a1.w;
        int i2 = bj[row];
        const float4* s2 = (const float4*)(E2 + (size_t)i2 * RANKn) + q * 2;
        float4 b0 = s2[0], b1 = s2[1];
        e2t[rb + 0][row] = b0.x; e2t[rb + 1][row] = b0.y; e2t[rb + 2][row] = b0.z; e2t[rb + 3][row] = b0.w;
        e2t[rb + 4][row] = b1.x; e2t[rb + 5][row] = b1.y; e2t[rb + 6][row] = b1.z; e2t[rb + 7][row] = b1.w;
    }
    __syncthreads();
    const int ti = t & 15, tj = t >> 4;
    const int i0 = ti * 4, j0 = tj * 4;
    float acc[4][4] = {};
    #pragma unroll
    for (int r = 0; r < RANKn; ++r) {
        float4 a = *(const float4*)&e1t[r][i0];
        float4 bb = *(const float4*)&e2t[r][j0];
        acc[0][0] += a.x * bb.x; acc[0][1] += a.x * bb.y; acc[0][2] += a.x * bb.z; acc[0][3] += a.x * bb.w;
        acc[1][0] += a.y * bb.x; acc[1][1] += a.y * bb.y; acc[1][2] += a.y * bb.z; acc[1][3] += a.y * bb.w;
        acc[2][0] += a.z * bb.x; acc[2][1] += a.z * bb.y; acc[2][2] += a.z * bb.z; acc[2][3] += a.z * bb.w;
        acc[3][0] += a.w * bb.x; acc[3][1] += a.w * bb.y; acc[3][2] += a.w * bb.z; acc[3][3] += a.w * bb.w;
    }
    float* outp = trans + (size_t)blk * (BEAMn * BEAMn);
    #pragma unroll
    for (int ii = 0; ii < 4; ++ii) {
        float4 o = { acc[ii][0], acc[ii][1], acc[ii][2], acc[ii][3] };
        *(float4*)&outp[(i0 + ii) * BEAMn + j0] = o;
    }
}

// sequential log-semiring scan; one block per batch; atomicAdd(-denominator)
__global__ __launch_bounds__(256) void scan_kernel(const float* __restrict__ trans,
                                                   const float* __restrict__ beam_val,
                                                   const int* __restrict__ mask,
                                                   float* __restrict__ out) {
    const int b = blockIdx.x;
    const int t = threadIdx.x;
    const int c = t >> 6, j = t & 63;
    const float* trb = trans + (size_t)b * (Sn - 1) * (BEAMn * BEAMn);
    const float* bv = beam_val + (size_t)b * Sn * BEAMn;
    const int* mk = mask + (size_t)b * Sn;
    __shared__ float score[BEAMn];
    __shared__ float psum[4][BEAMn];
    __shared__ float mshr;
    if (t < BEAMn) score[t] = bv[t];
    __syncthreads();
    if (t < BEAMn) {
        float v = score[t];
        for (int off = 32; off; off >>= 1) v = fmaxf(v, __shfl_xor(v, off, 64));
        if (t == 0) mshr = v;
    }
    __syncthreads();
    float m = mshr;
    // depth-2 register prefetch of this thread's 16 trans values per step
    float tcur[16], tnx1[16], tnx2[16];
    const float* tp0 = trb + c * 16 * BEAMn + j;
    #pragma unroll
    for (int r = 0; r < 16; ++r) tcur[r] = tp0[r * BEAMn];            // k=0
    #pragma unroll
    for (int r = 0; r < 16; ++r) tnx1[r] = tp0[4096 + r * BEAMn];     // k=1
    for (int k = 0; k < Sn - 1; ++k) {
        if (k + 2 < Sn - 1) {
            const float* tpn = tp0 + (size_t)(k + 2) * 4096;
            #pragma unroll
            for (int r = 0; r < 16; ++r) tnx2[r] = tpn[r * BEAMn];
        }
        float emitv = 0.f;
        if (t < BEAMn) emitv = bv[(size_t)(k + 1) * BEAMn + t];
        int mstep = mk[k + 1];
        float acc = 0.f;
        #pragma unroll
        for (int r = 0; r < 16; ++r) {
            acc += __expf(score[c * 16 + r] - m + tcur[r]);
        }
        psum[c][j] = acc;
        __syncthreads();
        if (t < BEAMn) {
            float tot = psum[0][t] + psum[1][t] + psum[2][t] + psum[3][t];
            float nxt = m + __logf(tot) + emitv;
            float sc = mstep ? nxt : score[t];
            score[t] = sc;
            float v = sc;
            for (int off = 32; off; off >>= 1) v = fmaxf(v, __shfl_xor(v, off, 64));
            if (t == 0) mshr = v;
        }
        __syncthreads();
        m = mshr;
        #pragma unroll
        for (int r = 0; r < 16; ++r) { tcur[r] = tnx1[r]; tnx1[r] = tnx2[r]; }
    }
    if (t < BEAMn) {
        float sc = score[t];
        float v = sc;
        for (int off = 32; off; off >>= 1) v = fmaxf(v, __shfl_xor(v, off, 64));
        float e = __expf(sc - v);
        for (int off = 32; off; off >>= 1) e += __shfl_xor(e, off, 64);
        if (t == 0) atomicAdd(out, -(v + __logf(e)));
    }
}

// numerator: sum over (b,s) of mask*(em + (s>0)*dot32(E1[tgt_prev],E2[tgt]))
__global__ __launch_bounds__(256) void num_kernel(const float* __restrict__ emis,
                                                  const int* __restrict__ targets,
                                                  const int* __restrict__ mask,
                                                  const float* __restrict__ E1,
                                                  const float* __restrict__ E2,
                                                  float* __restrict__ out) {
    const int gid = blockIdx.x * 256 + threadIdx.x;
    float val = 0.f;
    if (gid < Bn * Sn) {
        int s = gid & (Sn - 1);
        int tg = targets[gid];
        float em = emis[(size_t)gid * Vn + tg];
        float tr = 0.f;
        if (s > 0) {
            int pv = targets[gid - 1];
            const float4* p1 = (const float4*)(E1 + (size_t)pv * RANKn);
            const float4* p2 = (const float4*)(E2 + (size_t)tg * RANKn);
            #pragma unroll
            for (int r = 0; r < 8; ++r) {
                float4 a = p1[r], bb = p2[r];
                tr += a.x * bb.x + a.y * bb.y + a.z * bb.z + a.w * bb.w;
            }
        }
        if (mask[gid]) val = em + tr;
    }
    for (int off = 32; off; off >>= 1) val += __shfl_xor(val, off, 64);
    __shared__ float wsum[4];
    if ((threadIdx.x & 63) == 0) wsum[threadIdx.x >> 6] = val;
    __syncthreads();
    if (threadIdx.x == 0) atomicAdd(out, wsum[0] + wsum[1] + wsum[2] + wsum[3]);
}

extern "C" void kernel_launch(void* const* d_in, const int* in_sizes, int n_in,
                              void* d_out, int out_size, void* d_ws, size_t ws_size,
                              hipStream_t stream) {
    const float* emis    = (const float*)d_in[0];
    const int*   targets = (const int*)d_in[1];
    const int*   mask    = (const int*)d_in[2];   // bool input delivered as int32
    const float* E1      = (const float*)d_in[3];
    const float* E2      = (const float*)d_in[4];
    float* out = (float*)d_out;
    char* ws = (char*)d_ws;
    int*   beam_idx = (int*)ws;                          // 1 MB
    float* beam_val = (float*)(ws + (1 << 20));          // 1 MB
    float* trans    = (float*)(ws + (2 << 20));          // 16*255*4096*4 = 66.8 MB

    hipMemsetAsync(out, 0, sizeof(float), stream);
    hipLaunchKernelGGL(topk_kernel, dim3(Bn * Sn), dim3(256), 0, stream,
                       emis, targets, beam_idx, beam_val);
    hipLaunchKernelGGL(trans_kernel, dim3(Bn * (Sn - 1)), dim3(256), 0, stream,
                       E1, E2, beam_idx, trans);
    hipLaunchKernelGGL(num_kernel, dim3((Bn * Sn + 255) / 256), dim3(256), 0, stream,
                       emis, targets, mask, E1, E2, out);
    hipLaunchKernelGGL(scan_kernel, dim3(Bn), dim3(256), 0, stream,
                       trans, beam_val, mask, out);
}

// Round 5
// 719.711 us; speedup vs baseline: 1.0389x; 1.0389x over previous
//
#include <hip/hip_runtime.h>
#include <stdint.h>

#define Bn 16
#define Sn 256
#define Vn 21128
#define NV4 5282      // Vn/4 exactly
#define RANKn 32
#define BEAMn 64
#define HBINS 4096
#define CAPn 512
#define LOG2E 1.44269504088896340736f
#define LN2   0.69314718055994530942f

// v_exp_f32 / v_log_f32 are base-2; builtin names per clang BuiltinsAMDGPU:
#define EXP2F(x) __builtin_amdgcn_exp2f(x)
#define LOG2F(x) __builtin_amdgcn_logf(x)

__device__ __forceinline__ unsigned f2o(unsigned b) {  // float bits -> order-preserving uint
    return (b & 0x80000000u) ? ~b : (b | 0x80000000u);
}
__device__ __forceinline__ float o2f(unsigned u) {
    unsigned b = (u & 0x80000000u) ? (u ^ 0x80000000u) : ~u;
    return __uint_as_float(b);
}

// One block per (b,s) row: radix-select top-64, force-include target.
__global__ __launch_bounds__(256) void topk_kernel(const float* __restrict__ emis,
                                                   const int* __restrict__ targets,
                                                   int* __restrict__ beam_idx,
                                                   float* __restrict__ beam_val) {
    const int row = blockIdx.x;            // b*Sn + s
    const float* __restrict__ rowp = emis + (size_t)row * Vn;
    const int tgt = targets[row];
    __shared__ unsigned hist[HBINS];
    __shared__ unsigned csum[256];
    __shared__ unsigned cu[CAPn];
    __shared__ int      cix[CAPn];
    __shared__ int      selidx[BEAMn];
    __shared__ float    selval[BEAMn];
    __shared__ unsigned ccount;
    __shared__ int      binstar;
    __shared__ int      chunkc;
    __shared__ int      hastgt;
    const int t = threadIdx.x;
    for (int i = t; i < HBINS; i += 256) hist[i] = 0;
    if (t == 0) { ccount = 0; hastgt = 0; }
    __syncthreads();
    uint4 vals[21];
    #pragma unroll
    for (int it = 0; it < 21; ++it) {
        int v4 = t + it * 256;
        if (v4 < NV4) {
            const uint4 raw = ((const uint4*)rowp)[v4];
            uint4 u;
            u.x = f2o(raw.x); u.y = f2o(raw.y); u.z = f2o(raw.z); u.w = f2o(raw.w);
            vals[it] = u;
            atomicAdd(&hist[u.x >> 20], 1u);
            atomicAdd(&hist[u.y >> 20], 1u);
            atomicAdd(&hist[u.z >> 20], 1u);
            atomicAdd(&hist[u.w >> 20], 1u);
        }
    }
    __syncthreads();
    // coarse sums: 16 bins per thread
    unsigned cs = 0;
    #pragma unroll
    for (int i = 0; i < 16; ++i) cs += hist[t * 16 + i];
    csum[t] = cs;
    __syncthreads();
    // inclusive SUFFIX scan (Hillis-Steele)
    for (int off = 1; off < 256; off <<= 1) {
        unsigned v = csum[t] + ((t + off < 256) ? csum[t + off] : 0u);
        __syncthreads();
        csum[t] = v;
        __syncthreads();
    }
    if (csum[t] >= BEAMn && (t == 255 || csum[t + 1] < BEAMn)) chunkc = t;
    __syncthreads();
    if (t == 0) {
        int tc = chunkc;
        unsigned acc = (tc == 255) ? 0u : csum[tc + 1];
        int bs = tc * 16;
        for (int b2 = tc * 16 + 15; b2 >= tc * 16; --b2) {
            acc += hist[b2];
            if (acc >= BEAMn) { bs = b2; break; }
        }
        binstar = bs;
    }
    __syncthreads();
    const unsigned bstar = (unsigned)binstar;
    // collect candidates (bin >= bstar) from register-cached values
    #pragma unroll
    for (int it = 0; it < 21; ++it) {
        int v4 = t + it * 256;
        if (v4 < NV4) {
            uint4 u = vals[it];
            int bi = v4 * 4;
            if ((u.x >> 20) >= bstar) { unsigned p = atomicAdd(&ccount, 1u); if (p < CAPn) { cu[p] = u.x; cix[p] = bi;     } }
            if ((u.y >> 20) >= bstar) { unsigned p = atomicAdd(&ccount, 1u); if (p < CAPn) { cu[p] = u.y; cix[p] = bi + 1; } }
            if ((u.z >> 20) >= bstar) { unsigned p = atomicAdd(&ccount, 1u); if (p < CAPn) { cu[p] = u.z; cix[p] = bi + 2; } }
            if ((u.w >> 20) >= bstar) { unsigned p = atomicAdd(&ccount, 1u); if (p < CAPn) { cu[p] = u.w; cix[p] = bi + 3; } }
        }
    }
    __syncthreads();
    const int C = (int)min(ccount, (unsigned)CAPn);
    // exact rank (value desc, index asc tie-break — matches JAX stable top_k)
    for (int p = t; p < C; p += 256) {
        unsigned up = cu[p]; int ip = cix[p];
        int rank = 0;
        for (int q = 0; q < C; ++q) {
            unsigned uq = cu[q];
            rank += (uq > up) || (uq == up && cix[q] < ip);
        }
        if (rank < BEAMn) { selidx[rank] = ip; selval[rank] = o2f(up); }
    }
    __syncthreads();
    if (t < BEAMn && selidx[t] == tgt) hastgt = 1;
    __syncthreads();
    if (t == 0 && !hastgt) { selidx[BEAMn - 1] = tgt; selval[BEAMn - 1] = rowp[tgt]; }
    __syncthreads();
    if (t < BEAMn) {
        beam_idx[(size_t)row * BEAMn + t] = selidx[t];
        beam_val[(size_t)row * BEAMn + t] = selval[t];
    }
}

// beam_trans[b,k,i,j] = dot32(E1[beam[b,k,i]], E2[beam[b,k+1,j]]) * LOG2E
// (pre-scaled to base-2 log domain; consumed only by scan_kernel)
#define TPAD 68
__global__ __launch_bounds__(256) void trans_kernel(const float* __restrict__ E1,
                                                    const float* __restrict__ E2,
                                                    const int* __restrict__ beam_idx,
                                                    float* __restrict__ trans) {
    const int blk = blockIdx.x;           // b*(Sn-1) + k
    const int b = blk / (Sn - 1);
    const int k = blk - b * (Sn - 1);
    const int* bi = beam_idx + ((size_t)(b * Sn + k)) * BEAMn;
    const int* bj = beam_idx + ((size_t)(b * Sn + k + 1)) * BEAMn;
    __shared__ float e1t[RANKn][TPAD];   // [r][i]
    __shared__ float e2t[RANKn][TPAD];
    const int t = threadIdx.x;
    {
        const int row = t >> 2, q = t & 3;
        const int rb = q * 8;
        int i1 = bi[row];
        const float4* s1 = (const float4*)(E1 + (size_t)i1 * RANKn) + q * 2;
        float4 a0 = s1[0], a1 = s1[1];
        e1t[rb + 0][row] = a0.x; e1t[rb + 1][row] = a0.y; e1t[rb + 2][row] = a0.z; e1t[rb + 3][row] = a0.w;
        e1t[rb + 4][row] = a1.x; e1t[rb + 5][row] = a1.y; e1t[rb + 6][row] = a1.z; e1t[rb + 7][row] = a1.w;
        int i2 = bj[row];
        const float4* s2 = (const float4*)(E2 + (size_t)i2 * RANKn) + q * 2;
        float4 b0 = s2[0], b1 = s2[1];
        e2t[rb + 0][row] = b0.x; e2t[rb + 1][row] = b0.y; e2t[rb + 2][row] = b0.z; e2t[rb + 3][row] = b0.w;
        e2t[rb + 4][row] = b1.x; e2t[rb + 5][row] = b1.y; e2t[rb + 6][row] = b1.z; e2t[rb + 7][row] = b1.w;
    }
    __syncthreads();
    const int ti = t & 15, tj = t >> 4;
    const int i0 = ti * 4, j0 = tj * 4;
    float acc[4][4] = {};
    #pragma unroll
    for (int r = 0; r < RANKn; ++r) {
        float4 a = *(const float4*)&e1t[r][i0];
        float4 bb = *(const float4*)&e2t[r][j0];
        acc[0][0] += a.x * bb.x; acc[0][1] += a.x * bb.y; acc[0][2] += a.x * bb.z; acc[0][3] += a.x * bb.w;
        acc[1][0] += a.y * bb.x; acc[1][1] += a.y * bb.y; acc[1][2] += a.y * bb.z; acc[1][3] += a.y * bb.w;
        acc[2][0] += a.z * bb.x; acc[2][1] += a.z * bb.y; acc[2][2] += a.z * bb.z; acc[2][3] += a.z * bb.w;
        acc[3][0] += a.w * bb.x; acc[3][1] += a.w * bb.y; acc[3][2] += a.w * bb.z; acc[3][3] += a.w * bb.w;
    }
    float* outp = trans + (size_t)blk * (BEAMn * BEAMn);
    #pragma unroll
    for (int ii = 0; ii < 4; ++ii) {
        float4 o = { acc[ii][0] * LOG2E, acc[ii][1] * LOG2E, acc[ii][2] * LOG2E, acc[ii][3] * LOG2E };
        *(float4*)&outp[(i0 + ii) * BEAMn + j0] = o;
    }
}

// sequential log-semiring scan in base-2 domain; one block per batch (512 thr).
// stabilizer m = sc[0] (spread bounded << exp2 range); no per-step reduce.
__global__ __launch_bounds__(512) void scan_kernel(const float* __restrict__ trans,
                                                   const float* __restrict__ beam_val,
                                                   const int* __restrict__ mask,
                                                   float* __restrict__ out) {
    const int b = blockIdx.x;
    const int t = threadIdx.x;
    const int c = t >> 6, j = t & 63;     // c in [0,8): 8-row chunk of i; j = column
    const float* __restrict__ trb = trans + (size_t)b * (Sn - 1) * (BEAMn * BEAMn);
    const float* __restrict__ bv  = beam_val + (size_t)b * Sn * BEAMn;
    const int* __restrict__ mk = mask + (size_t)b * Sn;
    __shared__ float sc[BEAMn];           // base-2 scores
    __shared__ float psum[8][BEAMn + 1];  // partial sums, conflict-free layout
    __shared__ int   msk[Sn];
    for (int i = t; i < Sn; i += 512) msk[i] = mk[i];
    float score_reg = 0.f;
    if (t < BEAMn) { score_reg = bv[t] * LOG2E; sc[t] = score_reg; }
    // wave0 emit prefetch (depth-2), base-2 scaled
    float ecur = 0.f, enx1 = 0.f;
    if (t < BEAMn) { ecur = bv[BEAMn + t] * LOG2E; enx1 = bv[2 * BEAMn + t] * LOG2E; }
    // trans register prefetch (depth-2): 8 values per thread per step
    float tcur[8], tnx1[8], tnx2[8];
    const float* tp0 = trb + (c * 8) * BEAMn + j;
    #pragma unroll
    for (int r = 0; r < 8; ++r) tcur[r] = tp0[r * BEAMn];            // tile 0
    #pragma unroll
    for (int r = 0; r < 8; ++r) tnx1[r] = tp0[4096 + r * BEAMn];     // tile 1
    __syncthreads();
    for (int k = 0; k < Sn - 1; ++k) {
        // prefetch tile k+2 and emit k+3
        if (k + 2 < Sn - 1) {
            const float* tpn = tp0 + (size_t)(k + 2) * 4096;
            #pragma unroll
            for (int r = 0; r < 8; ++r) tnx2[r] = tpn[r * BEAMn];
        }
        float enx2 = 0.f;
        if (t < BEAMn && k + 3 < Sn) enx2 = bv[(size_t)(k + 3) * BEAMn + t] * LOG2E;
        const float mt = sc[0];
        const float4 sa = *(const float4*)&sc[c * 8];
        const float4 sb = *(const float4*)&sc[c * 8 + 4];
        float acc;
        acc  = EXP2F(sa.x - mt + tcur[0]);
        acc += EXP2F(sa.y - mt + tcur[1]);
        acc += EXP2F(sa.z - mt + tcur[2]);
        acc += EXP2F(sa.w - mt + tcur[3]);
        acc += EXP2F(sb.x - mt + tcur[4]);
        acc += EXP2F(sb.y - mt + tcur[5]);
        acc += EXP2F(sb.z - mt + tcur[6]);
        acc += EXP2F(sb.w - mt + tcur[7]);
        psum[c][j] = acc;
        #pragma unroll
        for (int r = 0; r < 8; ++r) { tcur[r] = tnx1[r]; tnx1[r] = tnx2[r]; }
        __syncthreads();
        if (t < BEAMn) {
            float tot = psum[0][t] + psum[1][t] + psum[2][t] + psum[3][t]
                      + psum[4][t] + psum[5][t] + psum[6][t] + psum[7][t];
            float nxt = mt + LOG2F(tot) + ecur;
            score_reg = msk[k + 1] ? nxt : score_reg;
            sc[t] = score_reg;
            ecur = enx1; enx1 = enx2;
        }
        __syncthreads();
    }
    if (t < BEAMn) {
        float v = score_reg;
        for (int off = 32; off; off >>= 1) v = fmaxf(v, __shfl_xor(v, off, 64));
        float e = EXP2F(score_reg - v);
        for (int off = 32; off; off >>= 1) e += __shfl_xor(e, off, 64);
        if (t == 0) atomicAdd(out, -LN2 * (v + LOG2F(e)));
    }
}

// numerator: sum over (b,s) of mask*(em + (s>0)*dot32(E1[tgt_prev],E2[tgt]))
__global__ __launch_bounds__(256) void num_kernel(const float* __restrict__ emis,
                                                  const int* __restrict__ targets,
                                                  const int* __restrict__ mask,
                                                  const float* __restrict__ E1,
                                                  const float* __restrict__ E2,
                                                  float* __restrict__ out) {
    const int gid = blockIdx.x * 256 + threadIdx.x;
    float val = 0.f;
    if (gid < Bn * Sn) {
        int s = gid & (Sn - 1);
        int tg = targets[gid];
        float em = emis[(size_t)gid * Vn + tg];
        float tr = 0.f;
        if (s > 0) {
            int pv = targets[gid - 1];
            const float4* p1 = (const float4*)(E1 + (size_t)pv * RANKn);
            const float4* p2 = (const float4*)(E2 + (size_t)tg * RANKn);
            #pragma unroll
            for (int r = 0; r < 8; ++r) {
                float4 a = p1[r], bb = p2[r];
                tr += a.x * bb.x + a.y * bb.y + a.z * bb.z + a.w * bb.w;
            }
        }
        if (mask[gid]) val = em + tr;
    }
    for (int off = 32; off; off >>= 1) val += __shfl_xor(val, off, 64);
    __shared__ float wsum[4];
    if ((threadIdx.x & 63) == 0) wsum[threadIdx.x >> 6] = val;
    __syncthreads();
    if (threadIdx.x == 0) atomicAdd(out, wsum[0] + wsum[1] + wsum[2] + wsum[3]);
}

extern "C" void kernel_launch(void* const* d_in, const int* in_sizes, int n_in,
                              void* d_out, int out_size, void* d_ws, size_t ws_size,
                              hipStream_t stream) {
    const float* emis    = (const float*)d_in[0];
    const int*   targets = (const int*)d_in[1];
    const int*   mask    = (const int*)d_in[2];   // bool input delivered as int32
    const float* E1      = (const float*)d_in[3];
    const float* E2      = (const float*)d_in[4];
    float* out = (float*)d_out;
    char* ws = (char*)d_ws;
    int*   beam_idx = (int*)ws;                          // 1 MB
    float* beam_val = (float*)(ws + (1 << 20));          // 1 MB
    float* trans    = (float*)(ws + (2 << 20));          // 16*255*4096*4 = 66.8 MB

    (void)hipMemsetAsync(out, 0, sizeof(float), stream);
    hipLaunchKernelGGL(topk_kernel, dim3(Bn * Sn), dim3(256), 0, stream,
                       emis, targets, beam_idx, beam_val);
    hipLaunchKernelGGL(trans_kernel, dim3(Bn * (Sn - 1)), dim3(256), 0, stream,
                       E1, E2, beam_idx, trans);
    hipLaunchKernelGGL(num_kernel, dim3((Bn * Sn + 255) / 256), dim3(256), 0, stream,
                       emis, targets, mask, E1, E2, out);
    hipLaunchKernelGGL(scan_kernel, dim3(Bn), dim3(512), 0, stream,
                       trans, beam_val, mask, out);
}

// Round 6
// 688.341 us; speedup vs baseline: 1.0862x; 1.0456x over previous
//
#include <hip/hip_runtime.h>
#include <stdint.h>

#define Bn 16
#define Sn 256
#define Vn 21128
#define NV4 5282      // Vn/4 exactly
#define RANKn 32
#define BEAMn 64
#define HBINS 4096
#define CAPn 512
#define LOG2E 1.44269504088896340736f
#define LN2   0.69314718055994530942f

// v_exp_f32 / v_log_f32 are base-2:
#define EXP2F(x) __builtin_amdgcn_exp2f(x)
#define LOG2F(x) __builtin_amdgcn_logf(x)

__device__ __forceinline__ unsigned f2o(unsigned b) {  // float bits -> order-preserving uint
    return (b & 0x80000000u) ? ~b : (b | 0x80000000u);
}
__device__ __forceinline__ float o2f(unsigned u) {
    unsigned b = (u & 0x80000000u) ? (u ^ 0x80000000u) : ~u;
    return __uint_as_float(b);
}
__device__ __forceinline__ float rdlane(float v, int lane) {
    return __int_as_float(__builtin_amdgcn_readlane(__float_as_int(v), lane));
}

// One block per (b,s) row: radix-select top-64, force-include target.
__global__ __launch_bounds__(256) void topk_kernel(const float* __restrict__ emis,
                                                   const int* __restrict__ targets,
                                                   int* __restrict__ beam_idx,
                                                   float* __restrict__ beam_val) {
    const int row = blockIdx.x;            // b*Sn + s
    const float* __restrict__ rowp = emis + (size_t)row * Vn;
    const int tgt = targets[row];
    __shared__ unsigned hist[HBINS];
    __shared__ unsigned csum[256];
    __shared__ unsigned cu[CAPn];
    __shared__ int      cix[CAPn];
    __shared__ int      selidx[BEAMn];
    __shared__ float    selval[BEAMn];
    __shared__ unsigned ccount;
    __shared__ int      binstar;
    __shared__ int      chunkc;
    __shared__ int      hastgt;
    const int t = threadIdx.x;
    for (int i = t; i < HBINS; i += 256) hist[i] = 0;
    if (t == 0) { ccount = 0; hastgt = 0; }
    __syncthreads();
    uint4 vals[21];
    #pragma unroll
    for (int it = 0; it < 21; ++it) {
        int v4 = t + it * 256;
        if (v4 < NV4) {
            const uint4 raw = ((const uint4*)rowp)[v4];
            uint4 u;
            u.x = f2o(raw.x); u.y = f2o(raw.y); u.z = f2o(raw.z); u.w = f2o(raw.w);
            vals[it] = u;
            atomicAdd(&hist[u.x >> 20], 1u);
            atomicAdd(&hist[u.y >> 20], 1u);
            atomicAdd(&hist[u.z >> 20], 1u);
            atomicAdd(&hist[u.w >> 20], 1u);
        }
    }
    __syncthreads();
    unsigned cs = 0;
    #pragma unroll
    for (int i = 0; i < 16; ++i) cs += hist[t * 16 + i];
    csum[t] = cs;
    __syncthreads();
    for (int off = 1; off < 256; off <<= 1) {
        unsigned v = csum[t] + ((t + off < 256) ? csum[t + off] : 0u);
        __syncthreads();
        csum[t] = v;
        __syncthreads();
    }
    if (csum[t] >= BEAMn && (t == 255 || csum[t + 1] < BEAMn)) chunkc = t;
    __syncthreads();
    if (t == 0) {
        int tc = chunkc;
        unsigned acc = (tc == 255) ? 0u : csum[tc + 1];
        int bs = tc * 16;
        for (int b2 = tc * 16 + 15; b2 >= tc * 16; --b2) {
            acc += hist[b2];
            if (acc >= BEAMn) { bs = b2; break; }
        }
        binstar = bs;
    }
    __syncthreads();
    const unsigned bstar = (unsigned)binstar;
    #pragma unroll
    for (int it = 0; it < 21; ++it) {
        int v4 = t + it * 256;
        if (v4 < NV4) {
            uint4 u = vals[it];
            int bi = v4 * 4;
            if ((u.x >> 20) >= bstar) { unsigned p = atomicAdd(&ccount, 1u); if (p < CAPn) { cu[p] = u.x; cix[p] = bi;     } }
            if ((u.y >> 20) >= bstar) { unsigned p = atomicAdd(&ccount, 1u); if (p < CAPn) { cu[p] = u.y; cix[p] = bi + 1; } }
            if ((u.z >> 20) >= bstar) { unsigned p = atomicAdd(&ccount, 1u); if (p < CAPn) { cu[p] = u.z; cix[p] = bi + 2; } }
            if ((u.w >> 20) >= bstar) { unsigned p = atomicAdd(&ccount, 1u); if (p < CAPn) { cu[p] = u.w; cix[p] = bi + 3; } }
        }
    }
    __syncthreads();
    const int C = (int)min(ccount, (unsigned)CAPn);
    for (int p = t; p < C; p += 256) {
        unsigned up = cu[p]; int ip = cix[p];
        int rank = 0;
        for (int q = 0; q < C; ++q) {
            unsigned uq = cu[q];
            rank += (uq > up) || (uq == up && cix[q] < ip);
        }
        if (rank < BEAMn) { selidx[rank] = ip; selval[rank] = o2f(up); }
    }
    __syncthreads();
    if (t < BEAMn && selidx[t] == tgt) hastgt = 1;
    __syncthreads();
    if (t == 0 && !hastgt) { selidx[BEAMn - 1] = tgt; selval[BEAMn - 1] = rowp[tgt]; }
    __syncthreads();
    if (t < BEAMn) {
        beam_idx[(size_t)row * BEAMn + t] = selidx[t];
        beam_val[(size_t)row * BEAMn + t] = selval[t];
    }
}

// beam_trans[b,k,i,j] = dot32(E1[beam[b,k,i]], E2[beam[b,k+1,j]]) * LOG2E
#define TPAD 68
__global__ __launch_bounds__(256) void trans_kernel(const float* __restrict__ E1,
                                                    const float* __restrict__ E2,
                                                    const int* __restrict__ beam_idx,
                                                    float* __restrict__ trans) {
    const int blk = blockIdx.x;           // b*(Sn-1) + k
    const int b = blk / (Sn - 1);
    const int k = blk - b * (Sn - 1);
    const int* bi = beam_idx + ((size_t)(b * Sn + k)) * BEAMn;
    const int* bj = beam_idx + ((size_t)(b * Sn + k + 1)) * BEAMn;
    __shared__ float e1t[RANKn][TPAD];
    __shared__ float e2t[RANKn][TPAD];
    const int t = threadIdx.x;
    {
        const int row = t >> 2, q = t & 3;
        const int rb = q * 8;
        int i1 = bi[row];
        const float4* s1 = (const float4*)(E1 + (size_t)i1 * RANKn) + q * 2;
        float4 a0 = s1[0], a1 = s1[1];
        e1t[rb + 0][row] = a0.x; e1t[rb + 1][row] = a0.y; e1t[rb + 2][row] = a0.z; e1t[rb + 3][row] = a0.w;
        e1t[rb + 4][row] = a1.x; e1t[rb + 5][row] = a1.y; e1t[rb + 6][row] = a1.z; e1t[rb + 7][row] = a1.w;
        int i2 = bj[row];
        const float4* s2 = (const float4*)(E2 + (size_t)i2 * RANKn) + q * 2;
        float4 b0 = s2[0], b1 = s2[1];
        e2t[rb + 0][row] = b0.x; e2t[rb + 1][row] = b0.y; e2t[rb + 2][row] = b0.z; e2t[rb + 3][row] = b0.w;
        e2t[rb + 4][row] = b1.x; e2t[rb + 5][row] = b1.y; e2t[rb + 6][row] = b1.z; e2t[rb + 7][row] = b1.w;
    }
    __syncthreads();
    const int ti = t & 15, tj = t >> 4;
    const int i0 = ti * 4, j0 = tj * 4;
    float acc[4][4] = {};
    #pragma unroll
    for (int r = 0; r < RANKn; ++r) {
        float4 a = *(const float4*)&e1t[r][i0];
        float4 bb = *(const float4*)&e2t[r][j0];
        acc[0][0] += a.x * bb.x; acc[0][1] += a.x * bb.y; acc[0][2] += a.x * bb.z; acc[0][3] += a.x * bb.w;
        acc[1][0] += a.y * bb.x; acc[1][1] += a.y * bb.y; acc[1][2] += a.y * bb.z; acc[1][3] += a.y * bb.w;
        acc[2][0] += a.z * bb.x; acc[2][1] += a.z * bb.y; acc[2][2] += a.z * bb.z; acc[2][3] += a.z * bb.w;
        acc[3][0] += a.w * bb.x; acc[3][1] += a.w * bb.y; acc[3][2] += a.w * bb.z; acc[3][3] += a.w * bb.w;
    }
    float* outp = trans + (size_t)blk * (BEAMn * BEAMn);
    #pragma unroll
    for (int ii = 0; ii < 4; ++ii) {
        float4 o = { acc[ii][0] * LOG2E, acc[ii][1] * LOG2E, acc[ii][2] * LOG2E, acc[ii][3] * LOG2E };
        *(float4*)&outp[(i0 + ii) * BEAMn + j0] = o;
    }
}

// Sequential log-semiring scan, base-2 domain. One block (512 thr) per batch.
// All waves redundantly maintain score[j] in lane j (bitwise identical), row
// scores fetched via readlane (no LDS round trip). One barrier per step with
// double-buffered psum. True depth-2 prefetch via named triple buffers
// (unroll-by-3 => no register shuffle => no vmcnt(0) in the step body).
__global__ __launch_bounds__(512) void scan_kernel(const float* __restrict__ trans,
                                                   const float* __restrict__ beam_val,
                                                   const int* __restrict__ mask,
                                                   float* __restrict__ out) {
    const int b = blockIdx.x;
    const int t = threadIdx.x;
    const int c = t >> 6, j = t & 63;     // c: 8-row chunk of i; j = column = lane
    const float* __restrict__ trb = trans + (size_t)b * (Sn - 1) * (BEAMn * BEAMn);
    const float* __restrict__ bv  = beam_val + (size_t)b * Sn * BEAMn;
    const int* __restrict__ mk = mask + (size_t)b * Sn;
    __shared__ float psum[2][8][BEAMn + 1];

    float score_reg = bv[j] * LOG2E;      // identical in every wave
    float tba[8], tbb[8], tbc[8];
    float eba, ebb, ebc;
    int   mba, mbb, mbc;
    const float* tp0 = trb + (c * 8) * BEAMn + j;
    #pragma unroll
    for (int r = 0; r < 8; ++r) tba[r] = tp0[r * BEAMn];           // tile 0
    #pragma unroll
    for (int r = 0; r < 8; ++r) tbb[r] = tp0[4096 + r * BEAMn];    // tile 1
    eba = bv[BEAMn + j] * LOG2E;          // emit row 1
    ebb = bv[2 * BEAMn + j] * LOG2E;      // emit row 2
    mba = mk[1]; mbb = mk[2];
    ebc = 0.f; mbc = 0;

#define SSTEP(K, TA, EA, MA, TC, EC, MC)  {                                   \
    if ((K) + 2 < Sn - 1) {                                                   \
        const float* tpn = tp0 + (size_t)((K) + 2) * 4096;                    \
        _Pragma("unroll")                                                     \
        for (int r = 0; r < 8; ++r) TC[r] = tpn[r * BEAMn];                   \
        EC = bv[(size_t)((K) + 3) * BEAMn + j] * LOG2E;                       \
        MC = mk[(K) + 3];                                                     \
    }                                                                         \
    const float mt = rdlane(score_reg, 0);                                    \
    float acc;                                                                \
    {                                                                         \
        float s0 = rdlane(score_reg, c * 8 + 0);                              \
        float s1 = rdlane(score_reg, c * 8 + 1);                              \
        float s2 = rdlane(score_reg, c * 8 + 2);                              \
        float s3 = rdlane(score_reg, c * 8 + 3);                              \
        float s4 = rdlane(score_reg, c * 8 + 4);                              \
        float s5 = rdlane(score_reg, c * 8 + 5);                              \
        float s6 = rdlane(score_reg, c * 8 + 6);                              \
        float s7 = rdlane(score_reg, c * 8 + 7);                              \
        acc  = EXP2F(s0 - mt + TA[0]);                                        \
        acc += EXP2F(s1 - mt + TA[1]);                                        \
        acc += EXP2F(s2 - mt + TA[2]);                                        \
        acc += EXP2F(s3 - mt + TA[3]);                                        \
        acc += EXP2F(s4 - mt + TA[4]);                                        \
        acc += EXP2F(s5 - mt + TA[5]);                                        \
        acc += EXP2F(s6 - mt + TA[6]);                                        \
        acc += EXP2F(s7 - mt + TA[7]);                                        \
    }                                                                         \
    psum[(K) & 1][c][j] = acc;                                                \
    __syncthreads();                                                          \
    {                                                                         \
        const float (*ps)[BEAMn + 1] = psum[(K) & 1];                         \
        float tot = ps[0][j] + ps[1][j] + ps[2][j] + ps[3][j]                 \
                  + ps[4][j] + ps[5][j] + ps[6][j] + ps[7][j];                \
        float nxt = mt + LOG2F(tot) + EA;                                     \
        score_reg = MA ? nxt : score_reg;                                     \
    }                                                                         \
}

    for (int kb = 0; kb < Sn - 1; kb += 3) {       // 255 = 3*85
        SSTEP(kb,     tba, eba, mba, tbc, ebc, mbc);
        SSTEP(kb + 1, tbb, ebb, mbb, tba, eba, mba);
        SSTEP(kb + 2, tbc, ebc, mbc, tbb, ebb, mbb);
    }
#undef SSTEP

    if (t < BEAMn) {
        float v = score_reg;
        for (int off = 32; off; off >>= 1) v = fmaxf(v, __shfl_xor(v, off, 64));
        float e = EXP2F(score_reg - v);
        for (int off = 32; off; off >>= 1) e += __shfl_xor(e, off, 64);
        if (t == 0) atomicAdd(out, -LN2 * (v + LOG2F(e)));
    }
}

// numerator: sum over (b,s) of mask*(em + (s>0)*dot32(E1[tgt_prev],E2[tgt]))
__global__ __launch_bounds__(256) void num_kernel(const float* __restrict__ emis,
                                                  const int* __restrict__ targets,
                                                  const int* __restrict__ mask,
                                                  const float* __restrict__ E1,
                                                  const float* __restrict__ E2,
                                                  float* __restrict__ out) {
    const int gid = blockIdx.x * 256 + threadIdx.x;
    float val = 0.f;
    if (gid < Bn * Sn) {
        int s = gid & (Sn - 1);
        int tg = targets[gid];
        float em = emis[(size_t)gid * Vn + tg];
        float tr = 0.f;
        if (s > 0) {
            int pv = targets[gid - 1];
            const float4* p1 = (const float4*)(E1 + (size_t)pv * RANKn);
            const float4* p2 = (const float4*)(E2 + (size_t)tg * RANKn);
            #pragma unroll
            for (int r = 0; r < 8; ++r) {
                float4 a = p1[r], bb = p2[r];
                tr += a.x * bb.x + a.y * bb.y + a.z * bb.z + a.w * bb.w;
            }
        }
        if (mask[gid]) val = em + tr;
    }
    for (int off = 32; off; off >>= 1) val += __shfl_xor(val, off, 64);
    __shared__ float wsum[4];
    if ((threadIdx.x & 63) == 0) wsum[threadIdx.x >> 6] = val;
    __syncthreads();
    if (threadIdx.x == 0) atomicAdd(out, wsum[0] + wsum[1] + wsum[2] + wsum[3]);
}

extern "C" void kernel_launch(void* const* d_in, const int* in_sizes, int n_in,
                              void* d_out, int out_size, void* d_ws, size_t ws_size,
                              hipStream_t stream) {
    const float* emis    = (const float*)d_in[0];
    const int*   targets = (const int*)d_in[1];
    const int*   mask    = (const int*)d_in[2];   // bool input delivered as int32
    const float* E1      = (const float*)d_in[3];
    const float* E2      = (const float*)d_in[4];
    float* out = (float*)d_out;
    char* ws = (char*)d_ws;
    int*   beam_idx = (int*)ws;                          // 1 MB
    float* beam_val = (float*)(ws + (1 << 20));          // 1 MB
    float* trans    = (float*)(ws + (2 << 20));          // 16*255*4096*4 = 66.8 MB

    (void)hipMemsetAsync(out, 0, sizeof(float), stream);
    hipLaunchKernelGGL(topk_kernel, dim3(Bn * Sn), dim3(256), 0, stream,
                       emis, targets, beam_idx, beam_val);
    hipLaunchKernelGGL(trans_kernel, dim3(Bn * (Sn - 1)), dim3(256), 0, stream,
                       E1, E2, beam_idx, trans);
    hipLaunchKernelGGL(num_kernel, dim3((Bn * Sn + 255) / 256), dim3(256), 0, stream,
                       emis, targets, mask, E1, E2, out);
    hipLaunchKernelGGL(scan_kernel, dim3(Bn), dim3(512), 0, stream,
                       trans, beam_val, mask, out);
}

// Round 7
// 674.132 us; speedup vs baseline: 1.1091x; 1.0211x over previous
//
#include <hip/hip_runtime.h>
#include <stdint.h>

#define Bn 16
#define Sn 256
#define Vn 21128
#define NV4 5282      // Vn/4 exactly
#define RANKn 32
#define BEAMn 64
#define HBINS 4096
#define CAPn 512
#define LOG2E 1.44269504088896340736f
#define LN2   0.69314718055994530942f

// v_exp_f32 / v_log_f32 are base-2:
#define EXP2F(x) __builtin_amdgcn_exp2f(x)
#define LOG2F(x) __builtin_amdgcn_logf(x)

__device__ __forceinline__ unsigned f2o(unsigned b) {  // float bits -> order-preserving uint
    return (b & 0x80000000u) ? ~b : (b | 0x80000000u);
}
__device__ __forceinline__ float o2f(unsigned u) {
    unsigned b = (u & 0x80000000u) ? (u ^ 0x80000000u) : ~u;
    return __uint_as_float(b);
}
__device__ __forceinline__ float rdlane(float v, int lane) {
    return __int_as_float(__builtin_amdgcn_readlane(__float_as_int(v), lane));
}

// One block per (b,s) row: radix-select top-64, force-include target.
__global__ __launch_bounds__(256) void topk_kernel(const float* __restrict__ emis,
                                                   const int* __restrict__ targets,
                                                   int* __restrict__ beam_idx,
                                                   float* __restrict__ beam_val) {
    const int row = blockIdx.x;            // b*Sn + s
    const float* __restrict__ rowp = emis + (size_t)row * Vn;
    const int tgt = targets[row];
    __shared__ unsigned hist[HBINS];
    __shared__ unsigned csum[256];
    __shared__ unsigned cu[CAPn];
    __shared__ int      cix[CAPn];
    __shared__ int      selidx[BEAMn];
    __shared__ float    selval[BEAMn];
    __shared__ unsigned ccount;
    __shared__ int      binstar;
    __shared__ int      chunkc;
    __shared__ int      hastgt;
    const int t = threadIdx.x;
    for (int i = t; i < HBINS; i += 256) hist[i] = 0;
    if (t == 0) { ccount = 0; hastgt = 0; }
    __syncthreads();
    uint4 vals[21];
    #pragma unroll
    for (int it = 0; it < 21; ++it) {
        int v4 = t + it * 256;
        if (v4 < NV4) {
            const uint4 raw = ((const uint4*)rowp)[v4];
            uint4 u;
            u.x = f2o(raw.x); u.y = f2o(raw.y); u.z = f2o(raw.z); u.w = f2o(raw.w);
            vals[it] = u;
            atomicAdd(&hist[u.x >> 20], 1u);
            atomicAdd(&hist[u.y >> 20], 1u);
            atomicAdd(&hist[u.z >> 20], 1u);
            atomicAdd(&hist[u.w >> 20], 1u);
        }
    }
    __syncthreads();
    unsigned cs = 0;
    #pragma unroll
    for (int i = 0; i < 16; ++i) cs += hist[t * 16 + i];
    csum[t] = cs;
    __syncthreads();
    for (int off = 1; off < 256; off <<= 1) {
        unsigned v = csum[t] + ((t + off < 256) ? csum[t + off] : 0u);
        __syncthreads();
        csum[t] = v;
        __syncthreads();
    }
    if (csum[t] >= BEAMn && (t == 255 || csum[t + 1] < BEAMn)) chunkc = t;
    __syncthreads();
    if (t == 0) {
        int tc = chunkc;
        unsigned acc = (tc == 255) ? 0u : csum[tc + 1];
        int bs = tc * 16;
        for (int b2 = tc * 16 + 15; b2 >= tc * 16; --b2) {
            acc += hist[b2];
            if (acc >= BEAMn) { bs = b2; break; }
        }
        binstar = bs;
    }
    __syncthreads();
    const unsigned bstar = (unsigned)binstar;
    #pragma unroll
    for (int it = 0; it < 21; ++it) {
        int v4 = t + it * 256;
        if (v4 < NV4) {
            uint4 u = vals[it];
            int bi = v4 * 4;
            if ((u.x >> 20) >= bstar) { unsigned p = atomicAdd(&ccount, 1u); if (p < CAPn) { cu[p] = u.x; cix[p] = bi;     } }
            if ((u.y >> 20) >= bstar) { unsigned p = atomicAdd(&ccount, 1u); if (p < CAPn) { cu[p] = u.y; cix[p] = bi + 1; } }
            if ((u.z >> 20) >= bstar) { unsigned p = atomicAdd(&ccount, 1u); if (p < CAPn) { cu[p] = u.z; cix[p] = bi + 2; } }
            if ((u.w >> 20) >= bstar) { unsigned p = atomicAdd(&ccount, 1u); if (p < CAPn) { cu[p] = u.w; cix[p] = bi + 3; } }
        }
    }
    __syncthreads();
    const int C = (int)min(ccount, (unsigned)CAPn);
    for (int p = t; p < C; p += 256) {
        unsigned up = cu[p]; int ip = cix[p];
        int rank = 0;
        for (int q = 0; q < C; ++q) {
            unsigned uq = cu[q];
            rank += (uq > up) || (uq == up && cix[q] < ip);
        }
        if (rank < BEAMn) { selidx[rank] = ip; selval[rank] = o2f(up); }
    }
    __syncthreads();
    if (t < BEAMn && selidx[t] == tgt) hastgt = 1;
    __syncthreads();
    if (t == 0 && !hastgt) { selidx[BEAMn - 1] = tgt; selval[BEAMn - 1] = rowp[tgt]; }
    __syncthreads();
    if (t < BEAMn) {
        beam_idx[(size_t)row * BEAMn + t] = selidx[t];
        beam_val[(size_t)row * BEAMn + t] = selval[t];
    }
}

// transM[b,k,i,j] = exp2( dot32(E1[beam[b,k,i]], E2[beam[b,k+1,j]]) * LOG2E )
// LINEAR domain (values ~[0.9,1.1]); consumed only by scan_kernel.
#define TPAD 68
__global__ __launch_bounds__(256) void trans_kernel(const float* __restrict__ E1,
                                                    const float* __restrict__ E2,
                                                    const int* __restrict__ beam_idx,
                                                    float* __restrict__ trans) {
    const int blk = blockIdx.x;           // b*(Sn-1) + k
    const int b = blk / (Sn - 1);
    const int k = blk - b * (Sn - 1);
    const int* bi = beam_idx + ((size_t)(b * Sn + k)) * BEAMn;
    const int* bj = beam_idx + ((size_t)(b * Sn + k + 1)) * BEAMn;
    __shared__ float e1t[RANKn][TPAD];
    __shared__ float e2t[RANKn][TPAD];
    const int t = threadIdx.x;
    {
        const int row = t >> 2, q = t & 3;
        const int rb = q * 8;
        int i1 = bi[row];
        const float4* s1 = (const float4*)(E1 + (size_t)i1 * RANKn) + q * 2;
        float4 a0 = s1[0], a1 = s1[1];
        e1t[rb + 0][row] = a0.x; e1t[rb + 1][row] = a0.y; e1t[rb + 2][row] = a0.z; e1t[rb + 3][row] = a0.w;
        e1t[rb + 4][row] = a1.x; e1t[rb + 5][row] = a1.y; e1t[rb + 6][row] = a1.z; e1t[rb + 7][row] = a1.w;
        int i2 = bj[row];
        const float4* s2 = (const float4*)(E2 + (size_t)i2 * RANKn) + q * 2;
        float4 b0 = s2[0], b1 = s2[1];
        e2t[rb + 0][row] = b0.x; e2t[rb + 1][row] = b0.y; e2t[rb + 2][row] = b0.z; e2t[rb + 3][row] = b0.w;
        e2t[rb + 4][row] = b1.x; e2t[rb + 5][row] = b1.y; e2t[rb + 6][row] = b1.z; e2t[rb + 7][row] = b1.w;
    }
    __syncthreads();
    const int ti = t & 15, tj = t >> 4;
    const int i0 = ti * 4, j0 = tj * 4;
    float acc[4][4] = {};
    #pragma unroll
    for (int r = 0; r < RANKn; ++r) {
        float4 a = *(const float4*)&e1t[r][i0];
        float4 bb = *(const float4*)&e2t[r][j0];
        acc[0][0] += a.x * bb.x; acc[0][1] += a.x * bb.y; acc[0][2] += a.x * bb.z; acc[0][3] += a.x * bb.w;
        acc[1][0] += a.y * bb.x; acc[1][1] += a.y * bb.y; acc[1][2] += a.y * bb.z; acc[1][3] += a.y * bb.w;
        acc[2][0] += a.z * bb.x; acc[2][1] += a.z * bb.y; acc[2][2] += a.z * bb.z; acc[2][3] += a.z * bb.w;
        acc[3][0] += a.w * bb.x; acc[3][1] += a.w * bb.y; acc[3][2] += a.w * bb.z; acc[3][3] += a.w * bb.w;
    }
    float* outp = trans + (size_t)blk * (BEAMn * BEAMn);
    #pragma unroll
    for (int ii = 0; ii < 4; ++ii) {
        float4 o = { EXP2F(acc[ii][0] * LOG2E), EXP2F(acc[ii][1] * LOG2E),
                     EXP2F(acc[ii][2] * LOG2E), EXP2F(acc[ii][3] * LOG2E) };
        *(float4*)&outp[(i0 + ii) * BEAMn + j0] = o;
    }
}

// Sequential scan, base-2 log scores + LINEAR transition matrix.
// One block (512 thr) per batch. All waves redundantly hold score[j] in lane j.
// Per step/lane: 1 exp2 (p_j), 8 readlane*fmac partials, 1 log2.
// Barrier is raw `s_waitcnt lgkmcnt(0); s_barrier` — does NOT drain vmcnt, so
// the named-register trans prefetch (depth 2 via unroll-3) stays in flight
// across steps (the __syncthreads vmcnt(0) drain was the 680ns/step stall).
__global__ __launch_bounds__(512) void scan_kernel(const float* __restrict__ trans,
                                                   const float* __restrict__ beam_val,
                                                   const int* __restrict__ mask,
                                                   float* __restrict__ out) {
    const int b = blockIdx.x;
    const int t = threadIdx.x;
    const int c = t >> 6, j = t & 63;     // c: 8-row chunk of i; j = column = lane
    const float* __restrict__ trb = trans + (size_t)b * (Sn - 1) * (BEAMn * BEAMn);
    const float* __restrict__ bv  = beam_val + (size_t)b * Sn * BEAMn;
    const int* __restrict__ mk = mask + (size_t)b * Sn;
    __shared__ float psum[2][8][BEAMn + 1];

    float score_reg = bv[j] * LOG2E;      // identical in every wave
    float tba[8], tbb[8], tbc[8];
    float eba, ebb, ebc;
    int   mba, mbb, mbc;
    const float* tp0 = trb + (c * 8) * BEAMn + j;
    #pragma unroll
    for (int r = 0; r < 8; ++r) tba[r] = tp0[r * BEAMn];           // tile 0
    #pragma unroll
    for (int r = 0; r < 8; ++r) tbb[r] = tp0[4096 + r * BEAMn];    // tile 1
    eba = bv[BEAMn + j] * LOG2E;
    ebb = bv[2 * BEAMn + j] * LOG2E;
    mba = mk[1]; mbb = mk[2];
    ebc = 0.f; mbc = 0;

#define SSTEP(K, TA, EA, MA, TC, EC, MC)  {                                   \
    if ((K) + 2 < Sn - 1) {                                                   \
        const float* tpn = tp0 + (size_t)((K) + 2) * 4096;                    \
        _Pragma("unroll")                                                     \
        for (int r = 0; r < 8; ++r) TC[r] = tpn[r * BEAMn];                   \
        EC = bv[(size_t)((K) + 3) * BEAMn + j] * LOG2E;                       \
        MC = mk[(K) + 3];                                                     \
    }                                                                         \
    const float mt = rdlane(score_reg, 0);                                    \
    const float pj = EXP2F(score_reg - mt);                                   \
    float acc;                                                                \
    acc  = rdlane(pj, c * 8 + 0) * TA[0];                                     \
    acc += rdlane(pj, c * 8 + 1) * TA[1];                                     \
    acc += rdlane(pj, c * 8 + 2) * TA[2];                                     \
    acc += rdlane(pj, c * 8 + 3) * TA[3];                                     \
    acc += rdlane(pj, c * 8 + 4) * TA[4];                                     \
    acc += rdlane(pj, c * 8 + 5) * TA[5];                                     \
    acc += rdlane(pj, c * 8 + 6) * TA[6];                                     \
    acc += rdlane(pj, c * 8 + 7) * TA[7];                                     \
    psum[(K) & 1][c][j] = acc;                                                \
    __asm__ volatile("s_waitcnt lgkmcnt(0)\n\ts_barrier" ::: "memory");       \
    {                                                                         \
        const float (*ps)[BEAMn + 1] = psum[(K) & 1];                         \
        float tot = ps[0][j] + ps[1][j] + ps[2][j] + ps[3][j]                 \
                  + ps[4][j] + ps[5][j] + ps[6][j] + ps[7][j];                \
        float nxt = mt + LOG2F(tot) + EA;                                     \
        score_reg = MA ? nxt : score_reg;                                     \
    }                                                                         \
}

    for (int kb = 0; kb < Sn - 1; kb += 3) {       // 255 = 3*85
        SSTEP(kb,     tba, eba, mba, tbc, ebc, mbc);
        SSTEP(kb + 1, tbb, ebb, mbb, tba, eba, mba);
        SSTEP(kb + 2, tbc, ebc, mbc, tbb, ebb, mbb);
    }
#undef SSTEP

    if (t < BEAMn) {
        float v = score_reg;
        for (int off = 32; off; off >>= 1) v = fmaxf(v, __shfl_xor(v, off, 64));
        float e = EXP2F(score_reg - v);
        for (int off = 32; off; off >>= 1) e += __shfl_xor(e, off, 64);
        if (t == 0) atomicAdd(out, -LN2 * (v + LOG2F(e)));
    }
}

// numerator: sum over (b,s) of mask*(em + (s>0)*dot32(E1[tgt_prev],E2[tgt]))
__global__ __launch_bounds__(256) void num_kernel(const float* __restrict__ emis,
                                                  const int* __restrict__ targets,
                                                  const int* __restrict__ mask,
                                                  const float* __restrict__ E1,
                                                  const float* __restrict__ E2,
                                                  float* __restrict__ out) {
    const int gid = blockIdx.x * 256 + threadIdx.x;
    float val = 0.f;
    if (gid < Bn * Sn) {
        int s = gid & (Sn - 1);
        int tg = targets[gid];
        float em = emis[(size_t)gid * Vn + tg];
        float tr = 0.f;
        if (s > 0) {
            int pv = targets[gid - 1];
            const float4* p1 = (const float4*)(E1 + (size_t)pv * RANKn);
            const float4* p2 = (const float4*)(E2 + (size_t)tg * RANKn);
            #pragma unroll
            for (int r = 0; r < 8; ++r) {
                float4 a = p1[r], bb = p2[r];
                tr += a.x * bb.x + a.y * bb.y + a.z * bb.z + a.w * bb.w;
            }
        }
        if (mask[gid]) val = em + tr;
    }
    for (int off = 32; off; off >>= 1) val += __shfl_xor(val, off, 64);
    __shared__ float wsum[4];
    if ((threadIdx.x & 63) == 0) wsum[threadIdx.x >> 6] = val;
    __syncthreads();
    if (threadIdx.x == 0) atomicAdd(out, wsum[0] + wsum[1] + wsum[2] + wsum[3]);
}

extern "C" void kernel_launch(void* const* d_in, const int* in_sizes, int n_in,
                              void* d_out, int out_size, void* d_ws, size_t ws_size,
                              hipStream_t stream) {
    const float* emis    = (const float*)d_in[0];
    const int*   targets = (const int*)d_in[1];
    const int*   mask    = (const int*)d_in[2];   // bool input delivered as int32
    const float* E1      = (const float*)d_in[3];
    const float* E2      = (const float*)d_in[4];
    float* out = (float*)d_out;
    char* ws = (char*)d_ws;
    int*   beam_idx = (int*)ws;                          // 1 MB
    float* beam_val = (float*)(ws + (1 << 20));          // 1 MB
    float* trans    = (float*)(ws + (2 << 20));          // 16*255*4096*4 = 66.8 MB

    (void)hipMemsetAsync(out, 0, sizeof(float), stream);
    hipLaunchKernelGGL(topk_kernel, dim3(Bn * Sn), dim3(256), 0, stream,
                       emis, targets, beam_idx, beam_val);
    hipLaunchKernelGGL(trans_kernel, dim3(Bn * (Sn - 1)), dim3(256), 0, stream,
                       E1, E2, beam_idx, trans);
    hipLaunchKernelGGL(num_kernel, dim3((Bn * Sn + 255) / 256), dim3(256), 0, stream,
                       emis, targets, mask, E1, E2, out);
    hipLaunchKernelGGL(scan_kernel, dim3(Bn), dim3(512), 0, stream,
                       trans, beam_val, mask, out);
}